// Round 2
// baseline (20523.953 us; speedup 1.0000x reference)
//
#include <hip/hip_runtime.h>
#include <math.h>

#define IN_DIM 8192
#define HID 128
#define NSTEPS 4096

__device__ __forceinline__ float sigm(float x) { return 1.f / (1.f + __expf(-x)); }
__device__ __forceinline__ float tanh_f(float x) {
    x = fminf(fmaxf(x, -15.f), 15.f);          // avoid inf/inf NaN
    float e = __expf(2.f * x);
    return (e - 1.f) / (e + 1.f);
}

// ---------------------------------------------------------------------------
// Kernel 1: M = W_enc @ W_dec  (128x128), cvec = W_enc@b_dec + b_enc,
//           e1 = W_enc@x0 + b_enc.  Grid: 128 blocks (one per row p), 128 thr.
// ---------------------------------------------------------------------------
__global__ __launch_bounds__(128) void k_precompute_M(
    const float* __restrict__ W_enc, const float* __restrict__ W_dec,
    const float* __restrict__ b_enc, const float* __restrict__ b_dec,
    const float* __restrict__ x0,
    float* __restrict__ M, float* __restrict__ cvec, float* __restrict__ e1)
{
    const int p = blockIdx.x;
    const int t = threadIdx.x;              // 0..127 (= output column q)
    __shared__ float wl[128];
    __shared__ float red[256];
    float m0 = 0.f, m1 = 0.f, m2 = 0.f, m3 = 0.f, cacc = 0.f, eacc = 0.f;
    for (int i0 = 0; i0 < IN_DIM; i0 += 128) {
        float w = W_enc[(size_t)p * IN_DIM + i0 + t];   // coalesced
        cacc = fmaf(w, b_dec[i0 + t], cacc);
        eacc = fmaf(w, x0[i0 + t], eacc);
        wl[t] = w;
        __syncthreads();
#pragma unroll 8
        for (int k = 0; k < 128; k += 4) {              // W_dec reads coalesced in t
            m0 = fmaf(wl[k],     W_dec[(size_t)(i0 + k) * HID + t], m0);
            m1 = fmaf(wl[k + 1], W_dec[(size_t)(i0 + k + 1) * HID + t], m1);
            m2 = fmaf(wl[k + 2], W_dec[(size_t)(i0 + k + 2) * HID + t], m2);
            m3 = fmaf(wl[k + 3], W_dec[(size_t)(i0 + k + 3) * HID + t], m3);
        }
        __syncthreads();
    }
    M[p * HID + t] = (m0 + m1) + (m2 + m3);
    red[t] = cacc; red[128 + t] = eacc;
    __syncthreads();
    for (int s = 64; s > 0; s >>= 1) {
        if (t < s) { red[t] += red[t + s]; red[128 + t] += red[128 + t + s]; }
        __syncthreads();
    }
    if (t == 0) { cvec[p] = red[0] + b_enc[p]; e1[p] = red[128] + b_enc[p]; }
}

// ---------------------------------------------------------------------------
// Kernel 2: G rows 0..383 = W_ih@M, rows 384..767 = W_hh (copy).
//           gb[0..383] = W_ih@cvec + bias, gb[384..767] = 0.
//           ig1 = W_ih@e1 + bias.  Grid: 768 blocks, 128 threads.
// ---------------------------------------------------------------------------
__global__ __launch_bounds__(128) void k_precompute_G(
    const float* __restrict__ W_ih, const float* __restrict__ W_hh,
    const float* __restrict__ bias, const float* __restrict__ M,
    const float* __restrict__ cvec, const float* __restrict__ e1,
    float* __restrict__ G, float* __restrict__ gb, float* __restrict__ ig1)
{
    const int r = blockIdx.x;
    const int q = threadIdx.x;
    if (r >= 384) {
        G[(size_t)r * HID + q] = W_hh[(size_t)(r - 384) * HID + q];
        if (q == 0) gb[r] = 0.f;
        return;
    }
    __shared__ float red[256];
    float a0 = 0.f, a1 = 0.f, a2 = 0.f, a3 = 0.f;
#pragma unroll 8
    for (int k = 0; k < HID; k += 4) {   // W_ih[r][k] scalar-uniform, M coalesced
        a0 = fmaf(W_ih[r * HID + k],     M[(k) * HID + q], a0);
        a1 = fmaf(W_ih[r * HID + k + 1], M[(k + 1) * HID + q], a1);
        a2 = fmaf(W_ih[r * HID + k + 2], M[(k + 2) * HID + q], a2);
        a3 = fmaf(W_ih[r * HID + k + 3], M[(k + 3) * HID + q], a3);
    }
    G[(size_t)r * HID + q] = (a0 + a1) + (a2 + a3);
    float wq = W_ih[r * HID + q];
    red[q] = wq * cvec[q];
    red[128 + q] = wq * e1[q];
    __syncthreads();
    for (int s = 64; s > 0; s >>= 1) {
        if (q < s) { red[q] += red[q + s]; red[128 + q] += red[128 + q + s]; }
        __syncthreads();
    }
    if (q == 0) { gb[r] = red[0] + bias[r]; ig1[r] = red[128] + bias[r]; }
}

// ---------------------------------------------------------------------------
// Kernel 3: sequential GRU scan. ONE block, 768 threads (12 waves on 1 CU,
// 3 waves/SIMD). Thread r owns row r of G in registers: 32 float4 = 128 VGPR,
// PINNED with an empty asm so the compiler cannot rematerialize the global
// loads inside the t-loop (R1: it did exactly that -> 15.9 ms).
// Per step: g = G@h + gb (768x128 matvec, h broadcast from LDS), gates on
// threads 0..127. H[t] = h_{t+1}.
// ---------------------------------------------------------------------------
__global__ __launch_bounds__(768, 3) void k_recurrence(
    const float* __restrict__ G, const float* __restrict__ gb,
    const float* __restrict__ ig1, const float* __restrict__ bias_n,
    float* __restrict__ H)
{
    const int r = threadIdx.x;              // 0..767
    __shared__ float h_lds[HID];
    __shared__ float g_lds[6 * HID];        // 768
    const float gbr = gb[r];
    const float bnr = (r < HID) ? bias_n[r] : 0.f;

    float4 wv[32];
    const float4* grow = (const float4*)(G + (size_t)r * HID);
#pragma unroll 32
    for (int k = 0; k < 32; ++k) wv[k] = grow[k];
    // Pin the 128 weight floats into VGPRs: values become asm outputs, so the
    // compiler can no longer fold them back into per-iteration global loads.
#pragma unroll 32
    for (int k = 0; k < 32; ++k)
        asm volatile("" : "+v"(wv[k].x), "+v"(wv[k].y), "+v"(wv[k].z), "+v"(wv[k].w));

    // step 1: h0 = 0 => hg = 0
    if (r < HID) {
        float ir = ig1[r], iz = ig1[HID + r], inn = ig1[2 * HID + r];
        float rg = sigm(ir), zg = sigm(iz);
        float ng = tanh_f(fmaf(rg, bnr, inn));
        float h1 = ng - zg * ng;            // n + z*(0 - n)
        h_lds[r] = h1;
        H[r] = h1;
    }
    __syncthreads();

    for (int t = 1; t < NSTEPS; ++t) {
        const float4* h4 = (const float4*)h_lds;
        float a0 = gbr, a1 = 0.f, a2 = 0.f, a3 = 0.f;
#pragma unroll 32
        for (int k = 0; k < 32; ++k) {      // wave-uniform LDS addr -> broadcast
            float4 hv = h4[k];
            a0 = fmaf(wv[k].x, hv.x, a0);
            a1 = fmaf(wv[k].y, hv.y, a1);
            a2 = fmaf(wv[k].z, hv.z, a2);
            a3 = fmaf(wv[k].w, hv.w, a3);
        }
        g_lds[r] = (a0 + a1) + (a2 + a3);
        __syncthreads();
        if (r < HID) {                      // waves 0,1 only; uniform branch
            float ir = g_lds[r], iz = g_lds[HID + r], inn = g_lds[2 * HID + r];
            float hr = g_lds[3 * HID + r], hz = g_lds[4 * HID + r], hn = g_lds[5 * HID + r];
            float rg = sigm(ir + hr);
            float zg = sigm(iz + hz);
            float ng = tanh_f(inn + rg * (hn + bnr));
            float hp = h_lds[r];
            float hnew = ng + zg * (hp - ng);
            h_lds[r] = hnew;
            H[(size_t)t * HID + r] = hnew;
        }
        __syncthreads();
    }
}

// ---------------------------------------------------------------------------
// Kernel 4: out[t][i] = dot(H[t][:], W_dec[i][:]) + b_dec[i]
// GEMM M=4096(t) N=8192(i) K=128, fp32 vector. 64x64 tiles, 256 threads,
// 4x4 micro-tile (strided by 16), XOR-swizzled LDS (64KB total, conflict-free).
// ---------------------------------------------------------------------------
__global__ __launch_bounds__(256) void k_decode(
    const float* __restrict__ H, const float* __restrict__ W_dec,
    const float* __restrict__ b_dec, float* __restrict__ out)
{
    __shared__ float4 As[64 * 32];   // [t][k4], k4 XOR-swizzled by (t&7)
    __shared__ float4 Bs[64 * 32];   // [i][k4]
    const int tid = threadIdx.x;
    const int t0 = blockIdx.y * 64;
    const int i0 = blockIdx.x * 64;
#pragma unroll 8
    for (int j = 0; j < 8; ++j) {
        int f = tid + 256 * j;        // 0..2047 float4s, coalesced
        int t = f >> 5;
        int k4 = f & 31;
        int sw = k4 ^ (t & 7);
        As[t * 32 + sw] = *(const float4*)(H + (size_t)(t0 + t) * HID + 4 * k4);
        Bs[t * 32 + sw] = *(const float4*)(W_dec + (size_t)(i0 + t) * HID + 4 * k4);
    }
    __syncthreads();
    const int tx = tid & 15, ty = tid >> 4;
    const int xa = ty & 7, xb = tx & 7;
    float acc[4][4] = {{0.f}};
#pragma unroll 8
    for (int k4 = 0; k4 < 32; ++k4) {
        float4 a[4], b[4];
        int ia = k4 ^ xa, ib = k4 ^ xb;
#pragma unroll
        for (int u = 0; u < 4; ++u) a[u] = As[(ty + 16 * u) * 32 + ia];
#pragma unroll
        for (int v = 0; v < 4; ++v) b[v] = Bs[(tx + 16 * v) * 32 + ib];
#pragma unroll
        for (int u = 0; u < 4; ++u)
#pragma unroll
            for (int v = 0; v < 4; ++v) {
                acc[u][v] = fmaf(a[u].x, b[v].x, acc[u][v]);
                acc[u][v] = fmaf(a[u].y, b[v].y, acc[u][v]);
                acc[u][v] = fmaf(a[u].z, b[v].z, acc[u][v]);
                acc[u][v] = fmaf(a[u].w, b[v].w, acc[u][v]);
            }
    }
#pragma unroll
    for (int u = 0; u < 4; ++u) {
        int t = t0 + ty + 16 * u;
#pragma unroll
        for (int v = 0; v < 4; ++v) {
            int i = i0 + tx + 16 * v;
            out[(size_t)t * IN_DIM + i] = acc[u][v] + b_dec[i];
        }
    }
}

// ---------------------------------------------------------------------------
extern "C" void kernel_launch(void* const* d_in, const int* in_sizes, int n_in,
                              void* d_out, int out_size, void* d_ws, size_t ws_size,
                              hipStream_t stream)
{
    const float* x0     = (const float*)d_in[0];
    const float* W_enc  = (const float*)d_in[1];
    const float* b_enc  = (const float*)d_in[2];
    const float* W_ih   = (const float*)d_in[3];
    const float* W_hh   = (const float*)d_in[4];
    const float* bias   = (const float*)d_in[5];
    const float* bias_n = (const float*)d_in[6];
    const float* W_dec  = (const float*)d_in[7];
    const float* b_dec  = (const float*)d_in[8];
    float* out = (float*)d_out;

    // workspace layout (floats): needs ~2.56 MB
    float* ws   = (float*)d_ws;
    float* M    = ws;                 // 16384
    float* cvec = ws + 16384;         // 128
    float* e1   = ws + 16512;         // 128
    float* ig1  = ws + 16640;         // 384
    float* gb   = ws + 17024;         // 768
    float* G    = ws + 17792;         // 98304   (16B-aligned)
    float* H    = ws + 116096;        // 524288  (16B-aligned)

    k_precompute_M<<<128, 128, 0, stream>>>(W_enc, W_dec, b_enc, b_dec, x0, M, cvec, e1);
    k_precompute_G<<<768, 128, 0, stream>>>(W_ih, W_hh, bias, M, cvec, e1, G, gb, ig1);
    k_recurrence<<<1, 768, 0, stream>>>(G, gb, ig1, bias_n, H);
    dim3 grid(IN_DIM / 64, NSTEPS / 64);
    k_decode<<<grid, 256, 0, stream>>>(H, W_dec, b_dec, out);
}

// Round 3
// 20457.843 us; speedup vs baseline: 1.0032x; 1.0032x over previous
//
#include <hip/hip_runtime.h>
#include <math.h>

#define IN_DIM 8192
#define HID 128
#define NSTEPS 4096

__device__ __forceinline__ float sigm(float x) { return 1.f / (1.f + __expf(-x)); }
__device__ __forceinline__ float tanh_f(float x) {
    x = fminf(fmaxf(x, -15.f), 15.f);          // avoid inf/inf NaN
    float e = __expf(2.f * x);
    return (e - 1.f) / (e + 1.f);
}

// ---------------------------------------------------------------------------
// Kernel 1: M = W_enc @ W_dec  (128x128), cvec = W_enc@b_dec + b_enc,
//           e1 = W_enc@x0 + b_enc.  Grid: 128 blocks (one per row p), 128 thr.
// ---------------------------------------------------------------------------
__global__ __launch_bounds__(128) void k_precompute_M(
    const float* __restrict__ W_enc, const float* __restrict__ W_dec,
    const float* __restrict__ b_enc, const float* __restrict__ b_dec,
    const float* __restrict__ x0,
    float* __restrict__ M, float* __restrict__ cvec, float* __restrict__ e1)
{
    const int p = blockIdx.x;
    const int t = threadIdx.x;              // 0..127 (= output column q)
    __shared__ float wl[128];
    __shared__ float red[256];
    float m0 = 0.f, m1 = 0.f, m2 = 0.f, m3 = 0.f, cacc = 0.f, eacc = 0.f;
    for (int i0 = 0; i0 < IN_DIM; i0 += 128) {
        float w = W_enc[(size_t)p * IN_DIM + i0 + t];   // coalesced
        cacc = fmaf(w, b_dec[i0 + t], cacc);
        eacc = fmaf(w, x0[i0 + t], eacc);
        wl[t] = w;
        __syncthreads();
#pragma unroll 8
        for (int k = 0; k < 128; k += 4) {              // W_dec reads coalesced in t
            m0 = fmaf(wl[k],     W_dec[(size_t)(i0 + k) * HID + t], m0);
            m1 = fmaf(wl[k + 1], W_dec[(size_t)(i0 + k + 1) * HID + t], m1);
            m2 = fmaf(wl[k + 2], W_dec[(size_t)(i0 + k + 2) * HID + t], m2);
            m3 = fmaf(wl[k + 3], W_dec[(size_t)(i0 + k + 3) * HID + t], m3);
        }
        __syncthreads();
    }
    M[p * HID + t] = (m0 + m1) + (m2 + m3);
    red[t] = cacc; red[128 + t] = eacc;
    __syncthreads();
    for (int s = 64; s > 0; s >>= 1) {
        if (t < s) { red[t] += red[t + s]; red[128 + t] += red[128 + t + s]; }
        __syncthreads();
    }
    if (t == 0) { cvec[p] = red[0] + b_enc[p]; e1[p] = red[128] + b_enc[p]; }
}

// ---------------------------------------------------------------------------
// Kernel 2: G rows 0..383 = W_ih@M, rows 384..767 = W_hh (copy).
//           gb[0..383] = W_ih@cvec + bias, gb[384..767] = 0.
//           ig1 = W_ih@e1 + bias.  Grid: 768 blocks, 128 threads.
// ---------------------------------------------------------------------------
__global__ __launch_bounds__(128) void k_precompute_G(
    const float* __restrict__ W_ih, const float* __restrict__ W_hh,
    const float* __restrict__ bias, const float* __restrict__ M,
    const float* __restrict__ cvec, const float* __restrict__ e1,
    float* __restrict__ G, float* __restrict__ gb, float* __restrict__ ig1)
{
    const int r = blockIdx.x;
    const int q = threadIdx.x;
    if (r >= 384) {
        G[(size_t)r * HID + q] = W_hh[(size_t)(r - 384) * HID + q];
        if (q == 0) gb[r] = 0.f;
        return;
    }
    __shared__ float red[256];
    float a0 = 0.f, a1 = 0.f, a2 = 0.f, a3 = 0.f;
#pragma unroll 8
    for (int k = 0; k < HID; k += 4) {   // W_ih[r][k] scalar-uniform, M coalesced
        a0 = fmaf(W_ih[r * HID + k],     M[(k) * HID + q], a0);
        a1 = fmaf(W_ih[r * HID + k + 1], M[(k + 1) * HID + q], a1);
        a2 = fmaf(W_ih[r * HID + k + 2], M[(k + 2) * HID + q], a2);
        a3 = fmaf(W_ih[r * HID + k + 3], M[(k + 3) * HID + q], a3);
    }
    G[(size_t)r * HID + q] = (a0 + a1) + (a2 + a3);
    float wq = W_ih[r * HID + q];
    red[q] = wq * cvec[q];
    red[128 + q] = wq * e1[q];
    __syncthreads();
    for (int s = 64; s > 0; s >>= 1) {
        if (q < s) { red[q] += red[q + s]; red[128 + q] += red[128 + q + s]; }
        __syncthreads();
    }
    if (q == 0) { gb[r] = red[0] + bias[r]; ig1[r] = red[128] + bias[r]; }
}

// ---------------------------------------------------------------------------
// Kernel 3: sequential GRU scan. ONE block, 768 threads (12 waves on 1 CU,
// 3 waves/SIMD). Thread r owns row r of G in 32 NAMED float4 registers.
// R2 lesson: backend targeted 6 waves/EU (2 blocks/CU needs VGPR<=85) and
// sank the G loads into the loop. amdgpu_waves_per_eu(3,3) clamps the
// occupancy target to exactly our single-block residency -> budget 170 VGPR.
// Named scalars (not an array) + asm pin prevent both alloca/scratch and
// load-sinking.
// ---------------------------------------------------------------------------
#define W_LIST(F) F(0) F(1) F(2) F(3) F(4) F(5) F(6) F(7) F(8) F(9) F(10) \
    F(11) F(12) F(13) F(14) F(15) F(16) F(17) F(18) F(19) F(20) F(21) F(22) \
    F(23) F(24) F(25) F(26) F(27) F(28) F(29) F(30) F(31)

__global__ __launch_bounds__(768)
__attribute__((amdgpu_waves_per_eu(3, 3)))
void k_recurrence(
    const float* __restrict__ G, const float* __restrict__ gb,
    const float* __restrict__ ig1, const float* __restrict__ bias_n,
    float* __restrict__ H)
{
    const int r = threadIdx.x;              // 0..767
    __shared__ float h_lds[HID];
    __shared__ float g_lds[6 * HID];        // 768
    const float gbr = gb[r];
    const float bnr = (r < HID) ? bias_n[r] : 0.f;

    const float4* grow = (const float4*)(G + (size_t)r * HID);
#define DECL_W(i) float4 w##i = grow[i];
    W_LIST(DECL_W)
#undef DECL_W
    // Pin: values become asm outputs -> not rederivable, must stay in VGPRs.
#define PIN_W(i) asm volatile("" : "+v"(w##i.x), "+v"(w##i.y), "+v"(w##i.z), "+v"(w##i.w));
    W_LIST(PIN_W)
#undef PIN_W

    // step 1: h0 = 0 => hg = 0
    if (r < HID) {
        float ir = ig1[r], iz = ig1[HID + r], inn = ig1[2 * HID + r];
        float rg = sigm(ir), zg = sigm(iz);
        float ng = tanh_f(fmaf(rg, bnr, inn));
        float h1 = ng - zg * ng;            // n + z*(0 - n)
        h_lds[r] = h1;
        H[r] = h1;
    }
    __syncthreads();

    for (int t = 1; t < NSTEPS; ++t) {
        const float4* h4 = (const float4*)h_lds;
        float a0 = gbr, a1 = 0.f, a2 = 0.f, a3 = 0.f;
#define FMA_W(i) { float4 hv = h4[i]; \
        a0 = fmaf(w##i.x, hv.x, a0); a1 = fmaf(w##i.y, hv.y, a1); \
        a2 = fmaf(w##i.z, hv.z, a2); a3 = fmaf(w##i.w, hv.w, a3); }
        W_LIST(FMA_W)
#undef FMA_W
        g_lds[r] = (a0 + a1) + (a2 + a3);
        __syncthreads();
        if (r < HID) {                      // waves 0,1 only; uniform branch
            float ir = g_lds[r], iz = g_lds[HID + r], inn = g_lds[2 * HID + r];
            float hr = g_lds[3 * HID + r], hz = g_lds[4 * HID + r], hn = g_lds[5 * HID + r];
            float rg = sigm(ir + hr);
            float zg = sigm(iz + hz);
            float ng = tanh_f(inn + rg * (hn + bnr));
            float hp = h_lds[r];
            float hnew = ng + zg * (hp - ng);
            h_lds[r] = hnew;
            H[(size_t)t * HID + r] = hnew;
        }
        __syncthreads();
    }
}

// ---------------------------------------------------------------------------
// Kernel 4: out[t][i] = dot(H[t][:], W_dec[i][:]) + b_dec[i]
// GEMM M=4096(t) N=8192(i) K=128, fp32 vector. 64x64 tiles, 256 threads,
// 4x4 micro-tile (strided by 16), XOR-swizzled LDS (64KB total, conflict-free).
// ---------------------------------------------------------------------------
__global__ __launch_bounds__(256) void k_decode(
    const float* __restrict__ H, const float* __restrict__ W_dec,
    const float* __restrict__ b_dec, float* __restrict__ out)
{
    __shared__ float4 As[64 * 32];   // [t][k4], k4 XOR-swizzled by (t&7)
    __shared__ float4 Bs[64 * 32];   // [i][k4]
    const int tid = threadIdx.x;
    const int t0 = blockIdx.y * 64;
    const int i0 = blockIdx.x * 64;
#pragma unroll 8
    for (int j = 0; j < 8; ++j) {
        int f = tid + 256 * j;        // 0..2047 float4s, coalesced
        int t = f >> 5;
        int k4 = f & 31;
        int sw = k4 ^ (t & 7);
        As[t * 32 + sw] = *(const float4*)(H + (size_t)(t0 + t) * HID + 4 * k4);
        Bs[t * 32 + sw] = *(const float4*)(W_dec + (size_t)(i0 + t) * HID + 4 * k4);
    }
    __syncthreads();
    const int tx = tid & 15, ty = tid >> 4;
    const int xa = ty & 7, xb = tx & 7;
    float acc[4][4] = {{0.f}};
#pragma unroll 8
    for (int k4 = 0; k4 < 32; ++k4) {
        float4 a[4], b[4];
        int ia = k4 ^ xa, ib = k4 ^ xb;
#pragma unroll
        for (int u = 0; u < 4; ++u) a[u] = As[(ty + 16 * u) * 32 + ia];
#pragma unroll
        for (int v = 0; v < 4; ++v) b[v] = Bs[(tx + 16 * v) * 32 + ib];
#pragma unroll
        for (int u = 0; u < 4; ++u)
#pragma unroll
            for (int v = 0; v < 4; ++v) {
                acc[u][v] = fmaf(a[u].x, b[v].x, acc[u][v]);
                acc[u][v] = fmaf(a[u].y, b[v].y, acc[u][v]);
                acc[u][v] = fmaf(a[u].z, b[v].z, acc[u][v]);
                acc[u][v] = fmaf(a[u].w, b[v].w, acc[u][v]);
            }
    }
#pragma unroll
    for (int u = 0; u < 4; ++u) {
        int t = t0 + ty + 16 * u;
#pragma unroll
        for (int v = 0; v < 4; ++v) {
            int i = i0 + tx + 16 * v;
            out[(size_t)t * IN_DIM + i] = acc[u][v] + b_dec[i];
        }
    }
}

// ---------------------------------------------------------------------------
extern "C" void kernel_launch(void* const* d_in, const int* in_sizes, int n_in,
                              void* d_out, int out_size, void* d_ws, size_t ws_size,
                              hipStream_t stream)
{
    const float* x0     = (const float*)d_in[0];
    const float* W_enc  = (const float*)d_in[1];
    const float* b_enc  = (const float*)d_in[2];
    const float* W_ih   = (const float*)d_in[3];
    const float* W_hh   = (const float*)d_in[4];
    const float* bias   = (const float*)d_in[5];
    const float* bias_n = (const float*)d_in[6];
    const float* W_dec  = (const float*)d_in[7];
    const float* b_dec  = (const float*)d_in[8];
    float* out = (float*)d_out;

    // workspace layout (floats): needs ~2.56 MB
    float* ws   = (float*)d_ws;
    float* M    = ws;                 // 16384
    float* cvec = ws + 16384;         // 128
    float* e1   = ws + 16512;         // 128
    float* ig1  = ws + 16640;         // 384
    float* gb   = ws + 17024;         // 768
    float* G    = ws + 17792;         // 98304   (16B-aligned)
    float* H    = ws + 116096;        // 524288  (16B-aligned)

    k_precompute_M<<<128, 128, 0, stream>>>(W_enc, W_dec, b_enc, b_dec, x0, M, cvec, e1);
    k_precompute_G<<<768, 128, 0, stream>>>(W_ih, W_hh, bias, M, cvec, e1, G, gb, ig1);
    k_recurrence<<<1, 768, 0, stream>>>(G, gb, ig1, bias_n, H);
    dim3 grid(IN_DIM / 64, NSTEPS / 64);
    k_decode<<<grid, 256, 0, stream>>>(H, W_dec, b_dec, out);
}

// Round 5
// 4313.148 us; speedup vs baseline: 4.7585x; 4.7431x over previous
//
#include <hip/hip_runtime.h>
#include <math.h>

#define IN_DIM 8192
#define HID 128
#define NSTEPS 4096

__device__ __forceinline__ float sigm(float x) { return 1.f / (1.f + __expf(-x)); }
__device__ __forceinline__ float tanh_f(float x) {
    x = fminf(fmaxf(x, -15.f), 15.f);          // avoid inf/inf NaN
    float e = __expf(2.f * x);
    return (e - 1.f) / (e + 1.f);
}

// ---------------------------------------------------------------------------
// Kernel 1: M = W_enc @ W_dec  (128x128), cvec = W_enc@b_dec + b_enc,
//           e1 = W_enc@x0 + b_enc.  Grid: 128 blocks (one per row p), 128 thr.
// ---------------------------------------------------------------------------
__global__ __launch_bounds__(128) void k_precompute_M(
    const float* __restrict__ W_enc, const float* __restrict__ W_dec,
    const float* __restrict__ b_enc, const float* __restrict__ b_dec,
    const float* __restrict__ x0,
    float* __restrict__ M, float* __restrict__ cvec, float* __restrict__ e1)
{
    const int p = blockIdx.x;
    const int t = threadIdx.x;              // 0..127 (= output column q)
    __shared__ float wl[128];
    __shared__ float red[256];
    float m0 = 0.f, m1 = 0.f, m2 = 0.f, m3 = 0.f, cacc = 0.f, eacc = 0.f;
    for (int i0 = 0; i0 < IN_DIM; i0 += 128) {
        float w = W_enc[(size_t)p * IN_DIM + i0 + t];   // coalesced
        cacc = fmaf(w, b_dec[i0 + t], cacc);
        eacc = fmaf(w, x0[i0 + t], eacc);
        wl[t] = w;
        __syncthreads();
#pragma unroll 8
        for (int k = 0; k < 128; k += 4) {              // W_dec reads coalesced in t
            m0 = fmaf(wl[k],     W_dec[(size_t)(i0 + k) * HID + t], m0);
            m1 = fmaf(wl[k + 1], W_dec[(size_t)(i0 + k + 1) * HID + t], m1);
            m2 = fmaf(wl[k + 2], W_dec[(size_t)(i0 + k + 2) * HID + t], m2);
            m3 = fmaf(wl[k + 3], W_dec[(size_t)(i0 + k + 3) * HID + t], m3);
        }
        __syncthreads();
    }
    M[p * HID + t] = (m0 + m1) + (m2 + m3);
    red[t] = cacc; red[128 + t] = eacc;
    __syncthreads();
    for (int s = 64; s > 0; s >>= 1) {
        if (t < s) { red[t] += red[t + s]; red[128 + t] += red[128 + t + s]; }
        __syncthreads();
    }
    if (t == 0) { cvec[p] = red[0] + b_enc[p]; e1[p] = red[128] + b_enc[p]; }
}

// ---------------------------------------------------------------------------
// Kernel 2: G rows 0..383 = W_ih@M, rows 384..767 = W_hh (copy).
//           gb[0..383] = W_ih@cvec + bias, gb[384..767] = 0.
//           ig1 = W_ih@e1 + bias.  Grid: 768 blocks, 128 threads.
// ---------------------------------------------------------------------------
__global__ __launch_bounds__(128) void k_precompute_G(
    const float* __restrict__ W_ih, const float* __restrict__ W_hh,
    const float* __restrict__ bias, const float* __restrict__ M,
    const float* __restrict__ cvec, const float* __restrict__ e1,
    float* __restrict__ G, float* __restrict__ gb, float* __restrict__ ig1)
{
    const int r = blockIdx.x;
    const int q = threadIdx.x;
    if (r >= 384) {
        G[(size_t)r * HID + q] = W_hh[(size_t)(r - 384) * HID + q];
        if (q == 0) gb[r] = 0.f;
        return;
    }
    __shared__ float red[256];
    float a0 = 0.f, a1 = 0.f, a2 = 0.f, a3 = 0.f;
#pragma unroll 8
    for (int k = 0; k < HID; k += 4) {   // W_ih[r][k] scalar-uniform, M coalesced
        a0 = fmaf(W_ih[r * HID + k],     M[(k) * HID + q], a0);
        a1 = fmaf(W_ih[r * HID + k + 1], M[(k + 1) * HID + q], a1);
        a2 = fmaf(W_ih[r * HID + k + 2], M[(k + 2) * HID + q], a2);
        a3 = fmaf(W_ih[r * HID + k + 3], M[(k + 3) * HID + q], a3);
    }
    G[(size_t)r * HID + q] = (a0 + a1) + (a2 + a3);
    float wq = W_ih[r * HID + q];
    red[q] = wq * cvec[q];
    red[128 + q] = wq * e1[q];
    __syncthreads();
    for (int s = 64; s > 0; s >>= 1) {
        if (q < s) { red[q] += red[q + s]; red[128 + q] += red[128 + q + s]; }
        __syncthreads();
    }
    if (q == 0) { gb[r] = red[0] + bias[r]; ig1[r] = red[128] + bias[r]; }
}

// ---------------------------------------------------------------------------
// Kernel 3: sequential GRU scan. ONE block, 1024 threads (16 waves, 4/SIMD).
// Lane-quad K-split: thread t handles K-quarter q=t&3 (k in [32q,32q+32))
// of rows r0, r0+256, r0+512 (r0=t>>2) -> 24 float4 = 96 weight VGPRs under
// the 128 budget of __launch_bounds__(1024, 4). Intra-quad __shfl_xor(1/2)
// combines the partial dots. h is replicated 4x in LDS at stride 132; the
// read pointer for quarter q is replica base (132q) PLUS the K-offset (32q)
// = 164q floats  [R4 BUG: was 132q alone -> every quad dotted h[0:32]].
// Bank check: quad lanes read banks {4i,4i+4,4i+8,4i+12} -> conflict-free.
// ---------------------------------------------------------------------------
#define K8(F) F(0) F(1) F(2) F(3) F(4) F(5) F(6) F(7)

__global__ __launch_bounds__(1024, 4) void k_recurrence(
    const float* __restrict__ G, const float* __restrict__ gb,
    const float* __restrict__ ig1, const float* __restrict__ bias_n,
    float* __restrict__ H)
{
    const int t  = threadIdx.x;          // 0..1023
    const int q  = t & 3;                // K-quarter: k in [32q, 32q+32)
    const int r0 = t >> 2;               // 0..255; rows r0, r0+256, r0+512
    __shared__ float h_rep[4 * 132];     // 4 copies of h, stride 132 floats
    __shared__ float g_lds[6 * HID];     // 768

    const float4* gp0 = (const float4*)(G + (size_t)(r0)       * HID + 32 * q);
    const float4* gp1 = (const float4*)(G + (size_t)(r0 + 256) * HID + 32 * q);
    const float4* gp2 = (const float4*)(G + (size_t)(r0 + 512) * HID + 32 * q);
#define DECL_W(i) float4 w0_##i = gp0[i]; float4 w1_##i = gp1[i]; float4 w2_##i = gp2[i];
    K8(DECL_W)
#undef DECL_W
    // Pin: loaded values become asm outputs -> cannot be rematerialized as
    // in-loop global loads.
#define PIN_W(i) \
    asm volatile("" : "+v"(w0_##i.x), "+v"(w0_##i.y), "+v"(w0_##i.z), "+v"(w0_##i.w)); \
    asm volatile("" : "+v"(w1_##i.x), "+v"(w1_##i.y), "+v"(w1_##i.z), "+v"(w1_##i.w)); \
    asm volatile("" : "+v"(w2_##i.x), "+v"(w2_##i.y), "+v"(w2_##i.z), "+v"(w2_##i.w));
    K8(PIN_W)
#undef PIN_W

    const float gb0 = gb[r0];
    const float gb1 = gb[r0 + 256];
    const float gb2 = gb[r0 + 512];
    const float bnr = (t < HID) ? bias_n[t] : 0.f;

    // step 1: h0 = 0 => hg = 0, use precomputed ig1
    if (t < HID) {
        float ir = ig1[t], iz = ig1[HID + t], inn = ig1[2 * HID + t];
        float rg = sigm(ir), zg = sigm(iz);
        float ng = tanh_f(fmaf(rg, bnr, inn));
        float h1 = ng - zg * ng;            // n + z*(0 - n)
        h_rep[t] = h1; h_rep[132 + t] = h1; h_rep[264 + t] = h1; h_rep[396 + t] = h1;
        H[t] = h1;
    }
    __syncthreads();

    // replica q base = 132q floats; K-quarter offset = +32q floats
    const float4* hq = (const float4*)(h_rep + 164 * q);
    for (int st = 1; st < NSTEPS; ++st) {
        float a0 = 0.f, a1 = 0.f, a2 = 0.f;
        // interleave rows so each accumulator's dep distance is 3 FMAs
#define FMA_K(i) { float4 hv = hq[i]; \
        a0 = fmaf(w0_##i.x, hv.x, a0); a1 = fmaf(w1_##i.x, hv.x, a1); a2 = fmaf(w2_##i.x, hv.x, a2); \
        a0 = fmaf(w0_##i.y, hv.y, a0); a1 = fmaf(w1_##i.y, hv.y, a1); a2 = fmaf(w2_##i.y, hv.y, a2); \
        a0 = fmaf(w0_##i.z, hv.z, a0); a1 = fmaf(w1_##i.z, hv.z, a1); a2 = fmaf(w2_##i.z, hv.z, a2); \
        a0 = fmaf(w0_##i.w, hv.w, a0); a1 = fmaf(w1_##i.w, hv.w, a1); a2 = fmaf(w2_##i.w, hv.w, a2); }
        K8(FMA_K)
#undef FMA_K
        // intra-quad reduction (lanes q, q^1, q^2 in same wave)
        a0 += __shfl_xor(a0, 1); a0 += __shfl_xor(a0, 2);
        a1 += __shfl_xor(a1, 1); a1 += __shfl_xor(a1, 2);
        a2 += __shfl_xor(a2, 1); a2 += __shfl_xor(a2, 2);
        if (q == 0) {
            g_lds[r0]       = a0 + gb0;
            g_lds[r0 + 256] = a1 + gb1;
            g_lds[r0 + 512] = a2 + gb2;
        }
        __syncthreads();
        if (t < HID) {                      // waves 0,1 only; uniform branch
            float ir = g_lds[t],           iz = g_lds[HID + t],     inn = g_lds[2 * HID + t];
            float hr = g_lds[3 * HID + t], hz = g_lds[4 * HID + t], hn = g_lds[5 * HID + t];
            float rg = sigm(ir + hr);
            float zg = sigm(iz + hz);
            float ng = tanh_f(inn + rg * (hn + bnr));
            float hp = h_rep[t];
            float hnew = ng + zg * (hp - ng);
            h_rep[t] = hnew; h_rep[132 + t] = hnew;
            h_rep[264 + t] = hnew; h_rep[396 + t] = hnew;
            H[(size_t)st * HID + t] = hnew;
        }
        __syncthreads();
    }
}

// ---------------------------------------------------------------------------
// Kernel 4: out[t][i] = dot(H[t][:], W_dec[i][:]) + b_dec[i]
// GEMM M=4096(t) N=8192(i) K=128, fp32 vector. 64x64 tiles, 256 threads,
// 4x4 micro-tile (strided by 16), XOR-swizzled LDS (64KB total, conflict-free).
// ---------------------------------------------------------------------------
__global__ __launch_bounds__(256) void k_decode(
    const float* __restrict__ H, const float* __restrict__ W_dec,
    const float* __restrict__ b_dec, float* __restrict__ out)
{
    __shared__ float4 As[64 * 32];   // [t][k4], k4 XOR-swizzled by (t&7)
    __shared__ float4 Bs[64 * 32];   // [i][k4]
    const int tid = threadIdx.x;
    const int t0 = blockIdx.y * 64;
    const int i0 = blockIdx.x * 64;
#pragma unroll 8
    for (int j = 0; j < 8; ++j) {
        int f = tid + 256 * j;        // 0..2047 float4s, coalesced
        int t = f >> 5;
        int k4 = f & 31;
        int sw = k4 ^ (t & 7);
        As[t * 32 + sw] = *(const float4*)(H + (size_t)(t0 + t) * HID + 4 * k4);
        Bs[t * 32 + sw] = *(const float4*)(W_dec + (size_t)(i0 + t) * HID + 4 * k4);
    }
    __syncthreads();
    const int tx = tid & 15, ty = tid >> 4;
    const int xa = ty & 7, xb = tx & 7;
    float acc[4][4] = {{0.f}};
#pragma unroll 8
    for (int k4 = 0; k4 < 32; ++k4) {
        float4 a[4], b[4];
        int ia = k4 ^ xa, ib = k4 ^ xb;
#pragma unroll
        for (int u = 0; u < 4; ++u) a[u] = As[(ty + 16 * u) * 32 + ia];
#pragma unroll
        for (int v = 0; v < 4; ++v) b[v] = Bs[(tx + 16 * v) * 32 + ib];
#pragma unroll
        for (int u = 0; u < 4; ++u)
#pragma unroll
            for (int v = 0; v < 4; ++v) {
                acc[u][v] = fmaf(a[u].x, b[v].x, acc[u][v]);
                acc[u][v] = fmaf(a[u].y, b[v].y, acc[u][v]);
                acc[u][v] = fmaf(a[u].z, b[v].z, acc[u][v]);
                acc[u][v] = fmaf(a[u].w, b[v].w, acc[u][v]);
            }
    }
#pragma unroll
    for (int u = 0; u < 4; ++u) {
        int t = t0 + ty + 16 * u;
#pragma unroll
        for (int v = 0; v < 4; ++v) {
            int i = i0 + tx + 16 * v;
            out[(size_t)t * IN_DIM + i] = acc[u][v] + b_dec[i];
        }
    }
}

// ---------------------------------------------------------------------------
extern "C" void kernel_launch(void* const* d_in, const int* in_sizes, int n_in,
                              void* d_out, int out_size, void* d_ws, size_t ws_size,
                              hipStream_t stream)
{
    const float* x0     = (const float*)d_in[0];
    const float* W_enc  = (const float*)d_in[1];
    const float* b_enc  = (const float*)d_in[2];
    const float* W_ih   = (const float*)d_in[3];
    const float* W_hh   = (const float*)d_in[4];
    const float* bias   = (const float*)d_in[5];
    const float* bias_n = (const float*)d_in[6];
    const float* W_dec  = (const float*)d_in[7];
    const float* b_dec  = (const float*)d_in[8];
    float* out = (float*)d_out;

    // workspace layout (floats): needs ~2.56 MB
    float* ws   = (float*)d_ws;
    float* M    = ws;                 // 16384
    float* cvec = ws + 16384;         // 128
    float* e1   = ws + 16512;         // 128
    float* ig1  = ws + 16640;         // 384
    float* gb   = ws + 17024;         // 768
    float* G    = ws + 17792;         // 98304   (16B-aligned)
    float* H    = ws + 116096;        // 524288  (16B-aligned)

    k_precompute_M<<<128, 128, 0, stream>>>(W_enc, W_dec, b_enc, b_dec, x0, M, cvec, e1);
    k_precompute_G<<<768, 128, 0, stream>>>(W_ih, W_hh, bias, M, cvec, e1, G, gb, ig1);
    k_recurrence<<<1, 1024, 0, stream>>>(G, gb, ig1, bias_n, H);
    dim3 grid(IN_DIM / 64, NSTEPS / 64);
    k_decode<<<grid, 256, 0, stream>>>(H, W_dec, b_dec, out);
}

// Round 6
// 3680.904 us; speedup vs baseline: 5.5758x; 1.1718x over previous
//
#include <hip/hip_runtime.h>
#include <math.h>

#define IN_DIM 8192
#define HID 128
#define NSTEPS 4096

typedef _Float16 f16x2 __attribute__((ext_vector_type(2)));
union F4H8 { float4 f4; f16x2 h[4]; };

__device__ __forceinline__ f16x2 cvt2(float2 p) {
    f16x2 r; r.x = (_Float16)p.x; r.y = (_Float16)p.y; return r;
}
__device__ __forceinline__ float sigm(float x) { return 1.f / (1.f + __expf(-x)); }
__device__ __forceinline__ float tanh_f(float x) {
    x = fminf(fmaxf(x, -15.f), 15.f);          // avoid inf/inf NaN
    float e = __expf(2.f * x);
    return (e - 1.f) / (e + 1.f);
}

// ---------------------------------------------------------------------------
// Kernel 1: M = W_enc @ W_dec  (128x128), cvec = W_enc@b_dec + b_enc,
//           e1 = W_enc@x0 + b_enc.  Grid: 128 blocks (one per row p), 128 thr.
// ---------------------------------------------------------------------------
__global__ __launch_bounds__(128) void k_precompute_M(
    const float* __restrict__ W_enc, const float* __restrict__ W_dec,
    const float* __restrict__ b_enc, const float* __restrict__ b_dec,
    const float* __restrict__ x0,
    float* __restrict__ M, float* __restrict__ cvec, float* __restrict__ e1)
{
    const int p = blockIdx.x;
    const int t = threadIdx.x;              // 0..127 (= output column q)
    __shared__ float wl[128];
    __shared__ float red[256];
    float m0 = 0.f, m1 = 0.f, m2 = 0.f, m3 = 0.f, cacc = 0.f, eacc = 0.f;
    for (int i0 = 0; i0 < IN_DIM; i0 += 128) {
        float w = W_enc[(size_t)p * IN_DIM + i0 + t];   // coalesced
        cacc = fmaf(w, b_dec[i0 + t], cacc);
        eacc = fmaf(w, x0[i0 + t], eacc);
        wl[t] = w;
        __syncthreads();
#pragma unroll 8
        for (int k = 0; k < 128; k += 4) {              // W_dec reads coalesced in t
            m0 = fmaf(wl[k],     W_dec[(size_t)(i0 + k) * HID + t], m0);
            m1 = fmaf(wl[k + 1], W_dec[(size_t)(i0 + k + 1) * HID + t], m1);
            m2 = fmaf(wl[k + 2], W_dec[(size_t)(i0 + k + 2) * HID + t], m2);
            m3 = fmaf(wl[k + 3], W_dec[(size_t)(i0 + k + 3) * HID + t], m3);
        }
        __syncthreads();
    }
    M[p * HID + t] = (m0 + m1) + (m2 + m3);
    red[t] = cacc; red[128 + t] = eacc;
    __syncthreads();
    for (int s = 64; s > 0; s >>= 1) {
        if (t < s) { red[t] += red[t + s]; red[128 + t] += red[128 + t + s]; }
        __syncthreads();
    }
    if (t == 0) { cvec[p] = red[0] + b_enc[p]; e1[p] = red[128] + b_enc[p]; }
}

// ---------------------------------------------------------------------------
// Kernel 2: G rows 0..383 = W_ih@M, rows 384..767 = W_hh (copy).
//           gb[0..383] = W_ih@cvec + bias, gb[384..767] = 0.
//           ig1 = W_ih@e1 + bias.  Grid: 768 blocks, 128 threads.
// ---------------------------------------------------------------------------
__global__ __launch_bounds__(128) void k_precompute_G(
    const float* __restrict__ W_ih, const float* __restrict__ W_hh,
    const float* __restrict__ bias, const float* __restrict__ M,
    const float* __restrict__ cvec, const float* __restrict__ e1,
    float* __restrict__ G, float* __restrict__ gb, float* __restrict__ ig1)
{
    const int r = blockIdx.x;
    const int q = threadIdx.x;
    if (r >= 384) {
        G[(size_t)r * HID + q] = W_hh[(size_t)(r - 384) * HID + q];
        if (q == 0) gb[r] = 0.f;
        return;
    }
    __shared__ float red[256];
    float a0 = 0.f, a1 = 0.f, a2 = 0.f, a3 = 0.f;
#pragma unroll 8
    for (int k = 0; k < HID; k += 4) {   // W_ih[r][k] scalar-uniform, M coalesced
        a0 = fmaf(W_ih[r * HID + k],     M[(k) * HID + q], a0);
        a1 = fmaf(W_ih[r * HID + k + 1], M[(k + 1) * HID + q], a1);
        a2 = fmaf(W_ih[r * HID + k + 2], M[(k + 2) * HID + q], a2);
        a3 = fmaf(W_ih[r * HID + k + 3], M[(k + 3) * HID + q], a3);
    }
    G[(size_t)r * HID + q] = (a0 + a1) + (a2 + a3);
    float wq = W_ih[r * HID + q];
    red[q] = wq * cvec[q];
    red[128 + q] = wq * e1[q];
    __syncthreads();
    for (int s = 64; s > 0; s >>= 1) {
        if (q < s) { red[q] += red[q + s]; red[128 + q] += red[128 + q + s]; }
        __syncthreads();
    }
    if (q == 0) { gb[r] = red[0] + bias[r]; ig1[r] = red[128] + bias[r]; }
}

// ---------------------------------------------------------------------------
// Kernel 3: sequential GRU scan. ONE block, 1024 threads (16 waves, 4/SIMD).
// R1-R5 lesson: the allocator targets ~60-85 VGPR no matter what hints we
// give; 96 f32 weights/thread always spill to scratch (R5: VGPR=60, ~1us/step
// scratch-BW bound). Fix: weights as f16 PAIRS -> 48 VGPRs/thread, computed
// with v_dot2_f32_f16 (f32 accumulate). Fits the allocator's comfort zone;
// halves FMA issue and h-broadcast LDS bytes too.
// Thread t: K-quarter q=t&3 (k in [32q,32q+32)) of rows r0, r0+256, r0+512
// (r0=t>>2). Intra-quad __shfl_xor(1/2) combines partials. h kept in f32
// (h_f32) for the gate math; f16 replicas (4x, 288B stride, read ptr 352q B
// -> banks {4i,4i+8,4i+16,4i+24} conflict-free) feed the matvec.
// ---------------------------------------------------------------------------
#define K16(F) F(0) F(1) F(2) F(3) F(4) F(5) F(6) F(7) F(8) F(9) F(10) F(11) \
    F(12) F(13) F(14) F(15)

__global__ __launch_bounds__(1024, 4)
__attribute__((amdgpu_waves_per_eu(4, 4)))
void k_recurrence(
    const float* __restrict__ G, const float* __restrict__ gb,
    const float* __restrict__ ig1, const float* __restrict__ bias_n,
    float* __restrict__ H)
{
    const int t  = threadIdx.x;          // 0..1023
    const int q  = t & 3;                // K-quarter: k in [32q, 32q+32)
    const int r0 = t >> 2;               // 0..255; rows r0, r0+256, r0+512
    __shared__ _Float16 h_rep[4 * 144];  // 4 replicas, stride 144 f16 = 288 B
    __shared__ float h_f32[HID];         // full-precision h for gate math
    __shared__ float g_lds[6 * HID];     // 768

    const float2* gp0 = (const float2*)(G + (size_t)(r0)       * HID + 32 * q);
    const float2* gp1 = (const float2*)(G + (size_t)(r0 + 256) * HID + 32 * q);
    const float2* gp2 = (const float2*)(G + (size_t)(r0 + 512) * HID + 32 * q);
#define DECL_W(i) f16x2 w0_##i = cvt2(gp0[i]); f16x2 w1_##i = cvt2(gp1[i]); \
                  f16x2 w2_##i = cvt2(gp2[i]);
    K16(DECL_W)
#undef DECL_W
    // Pin: converted values become asm outputs -> cannot be re-derived from
    // memory inside the loop. 48 VGPRs pinned.
#define PIN_W(i) asm volatile("" : "+v"(w0_##i), "+v"(w1_##i), "+v"(w2_##i));
    K16(PIN_W)
#undef PIN_W

    const float gb0 = gb[r0];
    const float gb1 = gb[r0 + 256];
    const float gb2 = gb[r0 + 512];
    const float bnr = (t < HID) ? bias_n[t] : 0.f;

    // step 1: h0 = 0 => hg = 0, use precomputed ig1
    if (t < HID) {
        float ir = ig1[t], iz = ig1[HID + t], inn = ig1[2 * HID + t];
        float rg = sigm(ir), zg = sigm(iz);
        float ng = tanh_f(fmaf(rg, bnr, inn));
        float h1 = ng - zg * ng;            // n + z*(0 - n)
        _Float16 h16 = (_Float16)h1;
        h_f32[t] = h1;
        h_rep[t] = h16; h_rep[144 + t] = h16;
        h_rep[288 + t] = h16; h_rep[432 + t] = h16;
        H[t] = h1;
    }
    __syncthreads();

    // replica q base = 288q B; K-quarter byte offset = 64q B -> 352q B total
    const float4* hq4 = (const float4*)((const char*)h_rep + 352 * q);
    for (int st = 1; st < NSTEPS; ++st) {
        float a0 = 0.f, a1 = 0.f, a2 = 0.f;
#define DOTB(j, iA, iB, iC, iD) { F4H8 u; u.f4 = hq4[j]; \
    a0 = __builtin_amdgcn_fdot2(w0_##iA, u.h[0], a0, false); \
    a1 = __builtin_amdgcn_fdot2(w1_##iA, u.h[0], a1, false); \
    a2 = __builtin_amdgcn_fdot2(w2_##iA, u.h[0], a2, false); \
    a0 = __builtin_amdgcn_fdot2(w0_##iB, u.h[1], a0, false); \
    a1 = __builtin_amdgcn_fdot2(w1_##iB, u.h[1], a1, false); \
    a2 = __builtin_amdgcn_fdot2(w2_##iB, u.h[1], a2, false); \
    a0 = __builtin_amdgcn_fdot2(w0_##iC, u.h[2], a0, false); \
    a1 = __builtin_amdgcn_fdot2(w1_##iC, u.h[2], a1, false); \
    a2 = __builtin_amdgcn_fdot2(w2_##iC, u.h[2], a2, false); \
    a0 = __builtin_amdgcn_fdot2(w0_##iD, u.h[3], a0, false); \
    a1 = __builtin_amdgcn_fdot2(w1_##iD, u.h[3], a1, false); \
    a2 = __builtin_amdgcn_fdot2(w2_##iD, u.h[3], a2, false); }
        DOTB(0, 0, 1, 2, 3)
        DOTB(1, 4, 5, 6, 7)
        DOTB(2, 8, 9, 10, 11)
        DOTB(3, 12, 13, 14, 15)
#undef DOTB
        // intra-quad reduction (lanes t, t^1, t^2, t^3 share r0)
        a0 += __shfl_xor(a0, 1); a0 += __shfl_xor(a0, 2);
        a1 += __shfl_xor(a1, 1); a1 += __shfl_xor(a1, 2);
        a2 += __shfl_xor(a2, 1); a2 += __shfl_xor(a2, 2);
        if (q == 0) {
            g_lds[r0]       = a0 + gb0;
            g_lds[r0 + 256] = a1 + gb1;
            g_lds[r0 + 512] = a2 + gb2;
        }
        __syncthreads();
        if (t < HID) {                      // waves 0,1 only; uniform branch
            float ir = g_lds[t],           iz = g_lds[HID + t],     inn = g_lds[2 * HID + t];
            float hr = g_lds[3 * HID + t], hz = g_lds[4 * HID + t], hn = g_lds[5 * HID + t];
            float rg = sigm(ir + hr);
            float zg = sigm(iz + hz);
            float ng = tanh_f(inn + rg * (hn + bnr));
            float hp = h_f32[t];
            float hnew = ng + zg * (hp - ng);
            _Float16 h16 = (_Float16)hnew;
            h_f32[t] = hnew;
            h_rep[t] = h16; h_rep[144 + t] = h16;
            h_rep[288 + t] = h16; h_rep[432 + t] = h16;
            H[(size_t)st * HID + t] = hnew;
        }
        __syncthreads();
    }
}

// ---------------------------------------------------------------------------
// Kernel 4: out[t][i] = dot(H[t][:], W_dec[i][:]) + b_dec[i]
// GEMM M=4096(t) N=8192(i) K=128, fp32 vector. 64x64 tiles, 256 threads,
// 4x4 micro-tile (strided by 16), XOR-swizzled LDS (64KB total, conflict-free).
// ---------------------------------------------------------------------------
__global__ __launch_bounds__(256) void k_decode(
    const float* __restrict__ H, const float* __restrict__ W_dec,
    const float* __restrict__ b_dec, float* __restrict__ out)
{
    __shared__ float4 As[64 * 32];   // [t][k4], k4 XOR-swizzled by (t&7)
    __shared__ float4 Bs[64 * 32];   // [i][k4]
    const int tid = threadIdx.x;
    const int t0 = blockIdx.y * 64;
    const int i0 = blockIdx.x * 64;
#pragma unroll 8
    for (int j = 0; j < 8; ++j) {
        int f = tid + 256 * j;        // 0..2047 float4s, coalesced
        int t = f >> 5;
        int k4 = f & 31;
        int sw = k4 ^ (t & 7);
        As[t * 32 + sw] = *(const float4*)(H + (size_t)(t0 + t) * HID + 4 * k4);
        Bs[t * 32 + sw] = *(const float4*)(W_dec + (size_t)(i0 + t) * HID + 4 * k4);
    }
    __syncthreads();
    const int tx = tid & 15, ty = tid >> 4;
    const int xa = ty & 7, xb = tx & 7;
    float acc[4][4] = {{0.f}};
#pragma unroll 8
    for (int k4 = 0; k4 < 32; ++k4) {
        float4 a[4], b[4];
        int ia = k4 ^ xa, ib = k4 ^ xb;
#pragma unroll
        for (int u = 0; u < 4; ++u) a[u] = As[(ty + 16 * u) * 32 + ia];
#pragma unroll
        for (int v = 0; v < 4; ++v) b[v] = Bs[(tx + 16 * v) * 32 + ib];
#pragma unroll
        for (int u = 0; u < 4; ++u)
#pragma unroll
            for (int v = 0; v < 4; ++v) {
                acc[u][v] = fmaf(a[u].x, b[v].x, acc[u][v]);
                acc[u][v] = fmaf(a[u].y, b[v].y, acc[u][v]);
                acc[u][v] = fmaf(a[u].z, b[v].z, acc[u][v]);
                acc[u][v] = fmaf(a[u].w, b[v].w, acc[u][v]);
            }
    }
#pragma unroll
    for (int u = 0; u < 4; ++u) {
        int t = t0 + ty + 16 * u;
#pragma unroll
        for (int v = 0; v < 4; ++v) {
            int i = i0 + tx + 16 * v;
            out[(size_t)t * IN_DIM + i] = acc[u][v] + b_dec[i];
        }
    }
}

// ---------------------------------------------------------------------------
extern "C" void kernel_launch(void* const* d_in, const int* in_sizes, int n_in,
                              void* d_out, int out_size, void* d_ws, size_t ws_size,
                              hipStream_t stream)
{
    const float* x0     = (const float*)d_in[0];
    const float* W_enc  = (const float*)d_in[1];
    const float* b_enc  = (const float*)d_in[2];
    const float* W_ih   = (const float*)d_in[3];
    const float* W_hh   = (const float*)d_in[4];
    const float* bias   = (const float*)d_in[5];
    const float* bias_n = (const float*)d_in[6];
    const float* W_dec  = (const float*)d_in[7];
    const float* b_dec  = (const float*)d_in[8];
    float* out = (float*)d_out;

    // workspace layout (floats): needs ~2.56 MB
    float* ws   = (float*)d_ws;
    float* M    = ws;                 // 16384
    float* cvec = ws + 16384;         // 128
    float* e1   = ws + 16512;         // 128
    float* ig1  = ws + 16640;         // 384
    float* gb   = ws + 17024;         // 768
    float* G    = ws + 17792;         // 98304   (16B-aligned)
    float* H    = ws + 116096;        // 524288  (16B-aligned)

    k_precompute_M<<<128, 128, 0, stream>>>(W_enc, W_dec, b_enc, b_dec, x0, M, cvec, e1);
    k_precompute_G<<<768, 128, 0, stream>>>(W_ih, W_hh, bias, M, cvec, e1, G, gb, ig1);
    k_recurrence<<<1, 1024, 0, stream>>>(G, gb, ig1, bias_n, H);
    dim3 grid(IN_DIM / 64, NSTEPS / 64);
    k_decode<<<grid, 256, 0, stream>>>(H, W_dec, b_dec, out);
}